// Round 1
// baseline (483.799 us; speedup 1.0000x reference)
//
#include <hip/hip_runtime.h>

// WeaveLayer: pure permutation.
//   out[b, yb*8 + hi*4 + px, xb*8 + wi*4 + py] = imgs[b, yb*4+py, xb*4+px, hi*2+wi]
// Shapes fixed by the harness: imgs (32, 768, 768, 4) f32 -> out (32, 1536, 1536, 1) f32.
//
// Thread strategy (no LDS needed):
//   One thread owns one input x position within one patch-row group (b, yb):
//   it loads the 4-channel float4 from each of the 4 rows py=0..3 (coalesced:
//   consecutive lanes -> consecutive x -> consecutive 16B), then the 16 held
//   floats are exactly the 4 output float4s (py runs along w inside a float4).
//   4x4 register transpose, 4 coalesced-by-line global float4 stores.

#define B_  32
#define Y_  768
#define X_  768
#define YB_ 192   // Y_/4
#define OW_ 1536  // 2*X_
#define OW4_ 384  // OW_/4

__global__ __launch_bounds__(256) void weave_kernel(
    const float4* __restrict__ in, float4* __restrict__ out)
{
    const int tid  = threadIdx.x;
    const int gid  = blockIdx.x;

    const int xblk = gid % 3;          // 768 / 256 = 3 blocks span x
    const int byb  = gid / 3;
    const int yb   = byb % YB_;
    const int b    = byb / YB_;
    const int x    = xblk * 256 + tid; // 0..767

    // input float4 index for row (yb*4 + py): (b*Y + yb*4 + py)*X + x
    const long ibase = ((long)(b * Y_ + yb * 4) * X_ + x);
    const float4 r0 = in[ibase];
    const float4 r1 = in[ibase + X_];
    const float4 r2 = in[ibase + 2 * X_];
    const float4 r3 = in[ibase + 3 * X_];

    const int px = x & 3;
    const int xb = x >> 2;

    // out float4 index: (b*1536 + row)*384 + (xb*2 + wi),
    //   row = yb*8 + hi*4 + px
    const long orow0 = (long)(b * 1536 + yb * 8 + px) * OW4_ + xb * 2;
    const long orow1 = orow0 + 4L * OW4_;  // hi = 1 rows

    out[orow0]     = make_float4(r0.x, r1.x, r2.x, r3.x); // q=0: hi=0, wi=0
    out[orow0 + 1] = make_float4(r0.y, r1.y, r2.y, r3.y); // q=1: hi=0, wi=1
    out[orow1]     = make_float4(r0.z, r1.z, r2.z, r3.z); // q=2: hi=1, wi=0
    out[orow1 + 1] = make_float4(r0.w, r1.w, r2.w, r3.w); // q=3: hi=1, wi=1
}

extern "C" void kernel_launch(void* const* d_in, const int* in_sizes, int n_in,
                              void* d_out, int out_size, void* d_ws, size_t ws_size,
                              hipStream_t stream) {
    (void)in_sizes; (void)n_in; (void)d_ws; (void)ws_size; (void)out_size;
    const float4* imgs = (const float4*)d_in[0];  // (32,768,768,4) f32, 16B groups
    float4* out = (float4*)d_out;                 // (32,1536,1536,1) f32

    // total threads = 32 * 192 * 768 = 4,718,592 -> 18432 blocks of 256
    const int grid = B_ * YB_ * 3;
    weave_kernel<<<grid, 256, 0, stream>>>(imgs, out);
}

// Round 2
// 480.530 us; speedup vs baseline: 1.0068x; 1.0068x over previous
//
#include <hip/hip_runtime.h>

// WeaveLayer: pure permutation.
//   out[b, yb*8 + hi*4 + px, xb*8 + wi*4 + py] = imgs[b, yb*4+py, xb*4+px, hi*2+wi]
// imgs (32,768,768,4) f32 -> out (32,1536,1536,1) f32. 604 MB total traffic.
//
// v2: LDS-staged stores. Phase 1 keeps v1's perfectly coalesced loads (each
// lane: 4 channel-float4s down one input column = 4x 1KB-dense load instrs)
// and the 4x4 register transpose, but instead of scattering the 4 output
// float4s across 4 output rows (16 half-filled lines per store instr in v1),
// writes them to a wave-private LDS tile laid out in OUTPUT order.
// Phase 2 reads LDS contiguously and stores dense: each store instr covers
// two fully-dense 512B runs = 8 full 128B lines, zero holes.
//
// LDS row stride 33 float4s (S % 8 == 1) -> both the phase-1 scattered writes
// and phase-2 contiguous reads distribute uniformly over the 8 16B-granule
// banks (the b128 minimum).

#define B_   32
#define Y_   768
#define X_   768
#define YB_  192   // Y_/4
#define OW4_ 384   // (2*X_)/4 : output row length in float4s
#define S_   33    // LDS row stride in float4s (32 + 1 pad)

__global__ __launch_bounds__(256) void weave_kernel(
    const float4* __restrict__ in, float4* __restrict__ out)
{
    __shared__ float4 lds[4 * 8 * S_];   // 4 waves x 8 rows x 33 float4s = 16.9 KB

    const int tid  = threadIdx.x;
    const int gid  = blockIdx.x;

    const int xblk = gid % 3;            // 768 / 256 = 3 blocks span x
    const int byb  = gid / 3;
    const int yb   = byb % YB_;
    const int b    = byb / YB_;

    const int w = tid >> 6;              // wave id 0..3
    const int l = tid & 63;              // lane

    // ---- Phase 1: coalesced loads + register transpose -> LDS (output order)
    const int x = xblk * 256 + tid;      // 0..767
    const long ibase = ((long)(b * Y_ + yb * 4) * X_ + x);
    const float4 r0 = in[ibase];
    const float4 r1 = in[ibase + X_];
    const float4 r2 = in[ibase + 2 * X_];
    const float4 r3 = in[ibase + 3 * X_];

    const int px = l & 3;
    const int xo = l >> 2;               // 0..15: xb offset within wave
    float4* wlds = &lds[w * (8 * S_)];

    wlds[ px      * S_ + xo * 2    ] = make_float4(r0.x, r1.x, r2.x, r3.x); // hi0 wi0
    wlds[ px      * S_ + xo * 2 + 1] = make_float4(r0.y, r1.y, r2.y, r3.y); // hi0 wi1
    wlds[(px + 4) * S_ + xo * 2    ] = make_float4(r0.z, r1.z, r2.z, r3.z); // hi1 wi0
    wlds[(px + 4) * S_ + xo * 2 + 1] = make_float4(r0.w, r1.w, r2.w, r3.w); // hi1 wi1

    __syncthreads();

    // ---- Phase 2: contiguous LDS reads -> dense global stores
    // Wave w owns out rows yb*8+[0,8), col4 range [xblk*128 + w*32, +32).
    const long obase = (long)(b * 1536 + yb * 8) * OW4_ + xblk * 128 + w * 32;
    #pragma unroll
    for (int j = 0; j < 4; ++j) {
        const int flat = j * 64 + l;
        const int row8 = flat >> 5;      // 0..7 = hi*4+px
        const int c    = flat & 31;      // col4 within wave segment
        out[obase + (long)row8 * OW4_ + c] = wlds[row8 * S_ + c];
    }
}

extern "C" void kernel_launch(void* const* d_in, const int* in_sizes, int n_in,
                              void* d_out, int out_size, void* d_ws, size_t ws_size,
                              hipStream_t stream) {
    (void)in_sizes; (void)n_in; (void)d_ws; (void)ws_size; (void)out_size;
    const float4* imgs = (const float4*)d_in[0];  // (32,768,768,4) f32, 16B px groups
    float4* out = (float4*)d_out;                 // (32,1536,1536,1) f32

    const int grid = B_ * YB_ * 3;                // 18432 blocks of 256
    weave_kernel<<<grid, 256, 0, stream>>>(imgs, out);
}